// Round 9
// baseline (19692.300 us; speedup 1.0000x reference)
//
#include <hip/hip_runtime.h>
#include <hip/hip_bf16.h>
#include <hip/hip_fp16.h>
#include <hip/hip_cooperative_groups.h>
#include <cmath>

// Problem constants
#define BATCH 16
#define SEQ 256
#define EMBED 512
#define HIDDEN 1024
#define GATES 4096       // 4*HIDDEN
#define VOCAB 32000
#define MROWS 4096       // BATCH*SEQ
#define LOGITS_SZ 131072000  // 16*256*32000

typedef unsigned short ushort_t;
typedef unsigned int uint_t;
typedef __attribute__((ext_vector_type(8))) __bf16 bf16x8;
typedef __attribute__((ext_vector_type(4))) float f32x4;

// ---------------- embedding gather ----------------
__global__ void embed_kernel(const int* __restrict__ x, const float* __restrict__ emb,
                             float* __restrict__ X0) {
    int r = blockIdx.x;            // r = s*16 + b
    int s = r >> 4, b = r & 15;
    int tok = x[b * SEQ + s];
    const float4* src = (const float4*)(emb + (size_t)tok * EMBED);
    float4* dst = (float4*)(X0 + (size_t)r * EMBED);
    for (int i = threadIdx.x; i < EMBED / 4; i += blockDim.x) dst[i] = src[i];
}

// ---------------- transpose + gate-interleave + BLOCK-TILED fp16 pack ----------------
// W [4096][1024] (rows = gate*1024 + j) -> T[cb][kOff+k][c16] fp16, where
// col' = j*4 + gate, cb = col'>>4, c16 = col'&15.
__global__ void transpose_f16_tiled(const float* __restrict__ W, ushort_t* __restrict__ T,
                                    int kOff, int kTot) {
    __shared__ float tile[32][33];
    int c0 = blockIdx.x * 32, r0 = blockIdx.y * 32;   // c0: k range, r0: W-row range
    int tx = threadIdx.x & 31, ty = threadIdx.x >> 5; // 256 threads: ty 0..7
    for (int i = ty; i < 32; i += 8)
        tile[i][tx] = W[(size_t)(r0 + i) * HIDDEN + (c0 + tx)];
    __syncthreads();
    int g = r0 >> 10, j0 = r0 & 1023;
    for (int i = ty; i < 32; i += 8) {
        int colp = (j0 + tx) * 4 + g;
        int cb = colp >> 4, c16 = colp & 15;
        int k = kOff + c0 + i;
        T[((size_t)cb * kTot + k) * 16 + c16] =
            __half_as_ushort(__float2half_rn(tile[tx][i]));
    }
}

// ---------------- fp32 -> bf16 hi/lo split: X[r][RL] -> Y[r][2*RL] ----------------
__device__ __forceinline__ unsigned f2bf(float f) {
    unsigned u = __float_as_uint(f);
    return (u + 0x7FFFu + ((u >> 16) & 1u)) >> 16;   // RNE
}

__global__ __launch_bounds__(256) void conv_hilo(const float* __restrict__ X,
                                                 ushort_t* __restrict__ Y, int RL) {
    size_t r = blockIdx.x;
    int k4 = threadIdx.x * 4;
    if (k4 >= RL) return;
    float4 v = *(const float4*)(X + r * RL + k4);
    unsigned h0 = f2bf(v.x), h1 = f2bf(v.y), h2 = f2bf(v.z), h3 = f2bf(v.w);
    unsigned l0 = f2bf(v.x - __uint_as_float(h0 << 16));
    unsigned l1 = f2bf(v.y - __uint_as_float(h1 << 16));
    unsigned l2 = f2bf(v.z - __uint_as_float(h2 << 16));
    unsigned l3 = f2bf(v.w - __uint_as_float(h3 << 16));
    uint2 hv, lv;
    hv.x = h0 | (h1 << 16); hv.y = h2 | (h3 << 16);
    lv.x = l0 | (l1 << 16); lv.y = l2 | (l3 << 16);
    *(uint2*)(Y + r * 2 * RL + k4) = hv;
    *(uint2*)(Y + r * 2 * RL + RL + k4) = lv;
}

// ---------------- split-bf16 MFMA GEMM ----------------
// C = A32 @ B32^T + b1 + b2 via up-to-3 passes: Ah*Bh (+ Al*Bh) (+ Ah*Bl), fp32 acc.
// flags bit0: row perm r -> (r&15)*SEQ + (r>>4); bit1: col perm c -> (c&1023)*4 + (c>>10)
__global__ __launch_bounds__(256) void gemm_bf16_mfma(
    const ushort_t* __restrict__ A, const ushort_t* __restrict__ B,
    const float* __restrict__ b1, const float* __restrict__ b2,
    float* __restrict__ C, int Kel, int ldc, int nBase, int flags, int segs) {
    __shared__ __align__(16) ushort_t As[128 * 32];
    __shared__ __align__(16) ushort_t Bs[128 * 32];
    int tid = threadIdx.x;
    int lane = tid & 63, wave = tid >> 6;
    int wm = wave >> 1, wn = wave & 1;

    // bijective XCD swizzle (nwg % 8 == 0 in all uses)
    int nx = gridDim.x;
    int nwg = nx * gridDim.y;
    int orig = blockIdx.y * nx + blockIdx.x;
    int s = (orig & 7) * (nwg >> 3) + (orig >> 3);
    int bm = s % nx, bn = s / nx;

    f32x4 acc[4][4];
#pragma unroll
    for (int m = 0; m < 4; m++)
#pragma unroll
        for (int n = 0; n < 4; n++) acc[m][n] = (f32x4){0.f, 0.f, 0.f, 0.f};

    int srow = tid >> 1;            // 0..127: staged row
    int skh = (tid & 1) * 16;       // ushort k-offset 0/16
    const ushort_t* Abase = A + (size_t)(bm * 128 + srow) * (2 * Kel) + skh;
    const ushort_t* Bbase = B + (size_t)(bn * 128 + srow) * (2 * Kel) + skh;
    int lr = lane & 15;
    int lk = (lane >> 4) * 8;

#pragma unroll 1
    for (int seg = 0; seg < segs; seg++) {
        int aoff = (seg == 1) ? Kel : 0;     // seg0: Ah*Bh, seg1: Al*Bh, seg2: Ah*Bl
        int boff = (seg == 2) ? Kel : 0;
        for (int k0 = 0; k0 < Kel; k0 += 32) {
            uint4 a0 = *(const uint4*)(Abase + aoff + k0);
            uint4 a1 = *(const uint4*)(Abase + aoff + k0 + 8);
            uint4 b0 = *(const uint4*)(Bbase + boff + k0);
            uint4 b1v = *(const uint4*)(Bbase + boff + k0 + 8);
            __syncthreads();
            *(uint4*)(As + srow * 32 + skh) = a0;
            *(uint4*)(As + srow * 32 + skh + 8) = a1;
            *(uint4*)(Bs + srow * 32 + skh) = b0;
            *(uint4*)(Bs + srow * 32 + skh + 8) = b1v;
            __syncthreads();
            bf16x8 af[4], bfv[4];
#pragma unroll
            for (int m = 0; m < 4; m++)
                af[m] = *(const bf16x8*)(As + (wm * 64 + m * 16 + lr) * 32 + lk);
#pragma unroll
            for (int n = 0; n < 4; n++)
                bfv[n] = *(const bf16x8*)(Bs + (wn * 64 + n * 16 + lr) * 32 + lk);
#pragma unroll
            for (int m = 0; m < 4; m++)
#pragma unroll
                for (int n = 0; n < 4; n++)
                    acc[m][n] = __builtin_amdgcn_mfma_f32_16x16x32_bf16(
                        af[m], bfv[n], acc[m][n], 0, 0, 0);
        }
    }

    // epilogue: C/D layout col=lane&15, row=(lane>>4)*4+j
    int lq = lane >> 4;
#pragma unroll
    for (int n = 0; n < 4; n++) {
        int c = bn * 128 + wn * 64 + n * 16 + lr;
        float bb = (b1 ? b1[c] : 0.f) + (b2 ? b2[c] : 0.f);
        int cw = (flags & 2) ? ((c & 1023) * 4 + (c >> 10)) : c;
#pragma unroll
        for (int m = 0; m < 4; m++) {
#pragma unroll
            for (int j = 0; j < 4; j++) {
                int r = bm * 128 + wm * 64 + m * 16 + lq * 4 + j;
                int orow = (flags & 1) ? ((r & 15) * SEQ + (r >> 4)) : r;
                C[(size_t)orow * ldc + nBase + cw] = acc[m][n][j] + bb;
            }
        }
    }
}

// ---------------- PERSISTENT cooperative LSTM layer kernel ----------------
// 256 blocks x 512 threads, 1 block/CU, all co-resident (cooperative launch).
// Block cb owns 16 gate-interleaved cols' = 4 hidden units x 4 gates.
// Weights (32 KB fp16) loaded to LDS ONCE; c-state in registers; 256 steps
// in one launch with grid.sync() between steps.
// LDS: wlds 32K + hs 32K + pt 8K + gv 1K = 73 KB.
__global__ __launch_bounds__(512, 1) void lstm_persistent(
    const ushort_t* __restrict__ Wt2,  // [256][1024][16] fp16 block-tiled (this layer)
    const float* __restrict__ G,       // [4096 rows][4096] gate-interleaved (incl. biases)
    ushort_t* __restrict__ HT,         // [2][16384] fp16 parity buffers [j][b] (this layer)
    float* __restrict__ c_st,          // [16][1024] (this layer)
    float* __restrict__ Hseq) {        // [4096 rows][1024] fp32
    namespace cg = cooperative_groups;
    cg::grid_group grid = cg::this_grid();
    __shared__ __align__(16) ushort_t wlds[16384];   // 32 KB
    __shared__ __align__(16) ushort_t hs[16384];     // 32 KB
    __shared__ float pt[2048];                       // 8 KB
    __shared__ float gv[256];                        // 1 KB
    int tid = threadIdx.x, cb = blockIdx.x;

    // preload this block's weight slice into LDS (once)
    const uint4* wsrc = (const uint4*)(Wt2 + (size_t)cb * 16384);
    for (int i = tid; i < 2048; i += 512) ((uint4*)wlds)[i] = wsrc[i];

    int c4 = tid & 3;
    int b = (tid >> 2) & 15;
    int kg = tid >> 6;                  // 0..7
    int jl = tid & 3, bb4 = tid >> 2;   // update-thread coords (tid<64)
    float creg = 0.f;
    if (tid < 64) creg = c_st[bb4 * 1024 + cb * 4 + jl];

    int par = 0;
    for (int t = 0; t < SEQ; t++) {
        // prefetch this step's G slice (consumed 2 barriers later)
        float greg = 0.f;
        if (tid < 256)
            greg = G[((size_t)(t * BATCH + (tid >> 4))) * GATES + cb * 16 + (tid & 15)];

        // stage h(t) fp16 into LDS (32 KB broadcast)
        const uint_t* hsrc = (const uint_t*)(HT + par * 16384);
        for (int i = tid; i < 8192; i += 512) ((uint_t*)hs)[i] = hsrc[i];
        __syncthreads();

        const ushort_t* wp = wlds + (kg * 128) * 16 + c4 * 4;
        const ushort_t* hp = hs + (kg * 128) * 16 + b;
        float4 acc = {0.f, 0.f, 0.f, 0.f};
#pragma unroll 8
        for (int kk = 0; kk < 128; kk++) {
            uint2 u = *(const uint2*)(wp + kk * 16);
            float2 f01 = __half22float2(*(const __half2*)&u.x);
            float2 f23 = __half22float2(*(const __half2*)&u.y);
            float h = __half2float(*(const __half*)(hp + kk * 16));
            acc.x += h * f01.x; acc.y += h * f01.y;
            acc.z += h * f23.x; acc.w += h * f23.y;
        }
        *(float4*)&pt[kg * 256 + b * 16 + c4 * 4] = acc;
        __syncthreads();

        if (tid < 256) {                 // reduce 8 K-chunks + base gates
            int c16 = tid & 15, bbb = tid >> 4;
            float g = greg;
#pragma unroll
            for (int q = 0; q < 8; q++) g += pt[q * 256 + bbb * 16 + c16];
            gv[tid] = g;                 // gv[bbb*16 + c16]
        }
        __syncthreads();

        if (tid < 64) {                  // state update: 4 j x 16 b
            float4 g4 = *(const float4*)&gv[bb4 * 16 + jl * 4];   // i,f,g,o
            float ig = 1.f / (1.f + __expf(-g4.x));
            float fg = 1.f / (1.f + __expf(-g4.y));
            float gg = tanhf(g4.z);
            float og = 1.f / (1.f + __expf(-g4.w));
            creg = fg * creg + ig * gg;
            float h = og * tanhf(creg);
            int j = cb * 4 + jl;
            HT[(par ^ 1) * 16384 + j * BATCH + bb4] =
                __half_as_ushort(__float2half_rn(h));
            Hseq[((size_t)(t * BATCH + bb4)) * HIDDEN + j] = h;
        }
        par ^= 1;
        grid.sync();                     // device-scope release/acquire + grid barrier
    }
    if (tid < 64) c_st[bb4 * 1024 + cb * 4 + jl] = creg;
}

// ---------------- init & tails ----------------
__global__ void init_state2(const float* __restrict__ h0, const float* __restrict__ c0,
                            float* __restrict__ c_ws, ushort_t* __restrict__ HT) {
    int gid = blockIdx.x * 256 + threadIdx.x;  // 32768
    c_ws[gid] = c0[gid];
    int l = gid >> 14, b = (gid >> 10) & 15, j = gid & 1023;
    HT[l * 32768 + j * BATCH + b] = __half_as_ushort(__float2half_rn(h0[gid])); // parity 0
}

__global__ void write_tails2(const ushort_t* __restrict__ HT, const float* __restrict__ c_ws,
                             float* __restrict__ out) {
    int gid = blockIdx.x * 256 + threadIdx.x;  // 32768
    int l = gid >> 14, b = (gid >> 10) & 15, j = gid & 1023;
    out[LOGITS_SZ + gid] =
        __half2float(__ushort_as_half(HT[l * 32768 + j * BATCH + b]));  // final parity 0
    out[LOGITS_SZ + 32768 + gid] = c_ws[gid];
}

// ---------------- launch ----------------
extern "C" void kernel_launch(void* const* d_in, const int* in_sizes, int n_in,
                              void* d_out, int out_size, void* d_ws, size_t ws_size,
                              hipStream_t stream) {
    const int* x = (const int*)d_in[0];
    const float* h0 = (const float*)d_in[1];
    const float* c0 = (const float*)d_in[2];
    const float* emb = (const float*)d_in[3];
    const float* W_ih0 = (const float*)d_in[4];
    const float* W_hh0 = (const float*)d_in[5];
    const float* b_ih0 = (const float*)d_in[6];
    const float* b_hh0 = (const float*)d_in[7];
    const float* W_ih1 = (const float*)d_in[8];
    const float* W_hh1 = (const float*)d_in[9];
    const float* b_ih1 = (const float*)d_in[10];
    const float* b_hh1 = (const float*)d_in[11];
    const float* fc_W = (const float*)d_in[12];
    const float* fc_b = (const float*)d_in[13];
    float* out = (float*)d_out;
    float* ws = (float*)d_ws;

    // workspace layout (float offsets) — R7 map + fp16 HT
    const size_t OFF_WT0 = 0;               // Wt2_0 fp16 tiled: 2,097,152 fl
    const size_t OFF_WT1 = 4194304;         // Wt2_1 fp16 tiled: 2,097,152 fl
    const size_t OFF_X0 = 8388608;          // 2,097,152
    const size_t OFF_G = 10485760;          // 16,777,216 (ends 27,262,976)
    const size_t OFF_H0S = 27262976;        // 4,194,304
    const size_t OFF_H1S = 31457280;        // 4,194,304 (ends 35,651,584)
    const size_t OFF_C = 35651584;          // 32,768 (2 layers)
    const size_t OFF_HT = 35684352;         // 2L x 2par x 16384 halfs = 32,768 fl

    ushort_t* HTp = (ushort_t*)(ws + OFF_HT);

    // phase overlays (regions dead at time of use):
    ushort_t* XHL = (ushort_t*)(ws + OFF_H0S);                 // [4096][1024] us
    ushort_t* WIH0HL = (ushort_t*)(ws + OFF_H0S + 2097152);    // [4096][1024] us
    ushort_t* AH1 = (ushort_t*)(ws + OFF_WT0);                 // [4096][2048] us (over Wt2_0, dead after L0)
    ushort_t* WIH1HL = (ushort_t*)(ws + OFF_H1S);              // [4096][2048] us
    ushort_t* Whl = (ushort_t*)ws;                             // [16000][2048] us (FC phase)
    ushort_t* Ahl = (ushort_t*)(ws + 16384000);                // [4096][2048] us

    init_state2<<<128, 256, 0, stream>>>(h0, c0, ws + OFF_C, HTp);
    embed_kernel<<<MROWS, 128, 0, stream>>>(x, emb, ws + OFF_X0);
    transpose_f16_tiled<<<dim3(32, 128), 256, 0, stream>>>(W_hh0, (ushort_t*)(ws + OFF_WT0), 0, 1024);
    transpose_f16_tiled<<<dim3(32, 128), 256, 0, stream>>>(W_hh1, (ushort_t*)(ws + OFF_WT1), 0, 1024);

    // layer-0 input projection: G = X0 @ W_ih0^T + b_ih0 + b_hh0 (gate-interleaved, 3-seg)
    conv_hilo<<<MROWS, 256, 0, stream>>>(ws + OFF_X0, XHL, EMBED);
    conv_hilo<<<GATES, 256, 0, stream>>>(W_ih0, WIH0HL, EMBED);
    gemm_bf16_mfma<<<dim3(32, 32), 256, 0, stream>>>(
        XHL, WIH0HL, b_ih0, b_hh0, ws + OFF_G, EMBED, GATES, 0, 2, 3);

    // layer-0 recurrence: ONE persistent cooperative launch
    {
        const ushort_t* wt = (const ushort_t*)(ws + OFF_WT0);
        const float* gp = ws + OFF_G;
        ushort_t* ht = HTp;
        float* cp = ws + OFF_C;
        float* hq = ws + OFF_H0S;
        void* args[] = {(void*)&wt, (void*)&gp, (void*)&ht, (void*)&cp, (void*)&hq};
        hipLaunchCooperativeKernel((void*)lstm_persistent, dim3(256), dim3(512),
                                   args, 0, stream);
    }

    // layer-1 input projection: G = H0S @ W_ih1^T + b_ih1 + b_hh1 (gate-interleaved, 3-seg)
    conv_hilo<<<MROWS, 256, 0, stream>>>(ws + OFF_H0S, AH1, HIDDEN);
    conv_hilo<<<GATES, 256, 0, stream>>>(W_ih1, WIH1HL, HIDDEN);
    gemm_bf16_mfma<<<dim3(32, 32), 256, 0, stream>>>(
        AH1, WIH1HL, b_ih1, b_hh1, ws + OFF_G, HIDDEN, GATES, 0, 2, 3);

    // layer-1 recurrence
    {
        const ushort_t* wt = (const ushort_t*)(ws + OFF_WT1);
        const float* gp = ws + OFF_G;
        ushort_t* ht = HTp + 32768;
        float* cp = ws + OFF_C + BATCH * HIDDEN;
        float* hq = ws + OFF_H1S;
        void* args[] = {(void*)&wt, (void*)&gp, (void*)&ht, (void*)&cp, (void*)&hq};
        hipLaunchCooperativeKernel((void*)lstm_persistent, dim3(256), dim3(512),
                                   args, 0, stream);
    }

    // FC via split-bf16 MFMA (2-seg): logits[b][s][v]
    conv_hilo<<<MROWS, 256, 0, stream>>>(ws + OFF_H1S, Ahl, HIDDEN);
    for (int half = 0; half < 2; half++) {
        conv_hilo<<<16000, 256, 0, stream>>>(fc_W + (size_t)half * 16000 * HIDDEN, Whl, HIDDEN);
        gemm_bf16_mfma<<<dim3(32, 125), 256, 0, stream>>>(
            Ahl, Whl, fc_b, nullptr, out, HIDDEN, VOCAB, half * 16000, 1, 2);
    }

    write_tails2<<<128, 256, 0, stream>>>(HTp, ws + OFF_C, out);
}

// Round 10
// 8544.137 us; speedup vs baseline: 2.3048x; 2.3048x over previous
//
#include <hip/hip_runtime.h>
#include <hip/hip_bf16.h>
#include <hip/hip_fp16.h>
#include <hip/hip_cooperative_groups.h>
#include <cmath>

// Problem constants
#define BATCH 16
#define SEQ 256
#define EMBED 512
#define HIDDEN 1024
#define GATES 4096       // 4*HIDDEN
#define VOCAB 32000
#define MROWS 4096       // BATCH*SEQ
#define LOGITS_SZ 131072000  // 16*256*32000
#define FLG_STRIDE 16    // one cacheline (64 B) per flag

typedef unsigned short ushort_t;
typedef unsigned int uint_t;
typedef __attribute__((ext_vector_type(8))) __bf16 bf16x8;
typedef __attribute__((ext_vector_type(4))) float f32x4;

// ---------------- embedding gather ----------------
__global__ void embed_kernel(const int* __restrict__ x, const float* __restrict__ emb,
                             float* __restrict__ X0) {
    int r = blockIdx.x;            // r = s*16 + b
    int s = r >> 4, b = r & 15;
    int tok = x[b * SEQ + s];
    const float4* src = (const float4*)(emb + (size_t)tok * EMBED);
    float4* dst = (float4*)(X0 + (size_t)r * EMBED);
    for (int i = threadIdx.x; i < EMBED / 4; i += blockDim.x) dst[i] = src[i];
}

// ---------------- transpose + gate-interleave + BLOCK-TILED fp16 pack ----------------
// W [4096][1024] (rows = gate*1024 + j) -> T[cb][kOff+k][c16] fp16, where
// col' = j*4 + gate, cb = col'>>4, c16 = col'&15.
__global__ void transpose_f16_tiled(const float* __restrict__ W, ushort_t* __restrict__ T,
                                    int kOff, int kTot) {
    __shared__ float tile[32][33];
    int c0 = blockIdx.x * 32, r0 = blockIdx.y * 32;   // c0: k range, r0: W-row range
    int tx = threadIdx.x & 31, ty = threadIdx.x >> 5; // 256 threads: ty 0..7
    for (int i = ty; i < 32; i += 8)
        tile[i][tx] = W[(size_t)(r0 + i) * HIDDEN + (c0 + tx)];
    __syncthreads();
    int g = r0 >> 10, j0 = r0 & 1023;
    for (int i = ty; i < 32; i += 8) {
        int colp = (j0 + tx) * 4 + g;
        int cb = colp >> 4, c16 = colp & 15;
        int k = kOff + c0 + i;
        T[((size_t)cb * kTot + k) * 16 + c16] =
            __half_as_ushort(__float2half_rn(tile[tx][i]));
    }
}

// ---------------- fp32 -> bf16 hi/lo split: X[r][RL] -> Y[r][2*RL] ----------------
__device__ __forceinline__ unsigned f2bf(float f) {
    unsigned u = __float_as_uint(f);
    return (u + 0x7FFFu + ((u >> 16) & 1u)) >> 16;   // RNE
}

__global__ __launch_bounds__(256) void conv_hilo(const float* __restrict__ X,
                                                 ushort_t* __restrict__ Y, int RL) {
    size_t r = blockIdx.x;
    int k4 = threadIdx.x * 4;
    if (k4 >= RL) return;
    float4 v = *(const float4*)(X + r * RL + k4);
    unsigned h0 = f2bf(v.x), h1 = f2bf(v.y), h2 = f2bf(v.z), h3 = f2bf(v.w);
    unsigned l0 = f2bf(v.x - __uint_as_float(h0 << 16));
    unsigned l1 = f2bf(v.y - __uint_as_float(h1 << 16));
    unsigned l2 = f2bf(v.z - __uint_as_float(h2 << 16));
    unsigned l3 = f2bf(v.w - __uint_as_float(h3 << 16));
    uint2 hv, lv;
    hv.x = h0 | (h1 << 16); hv.y = h2 | (h3 << 16);
    lv.x = l0 | (l1 << 16); lv.y = l2 | (l3 << 16);
    *(uint2*)(Y + r * 2 * RL + k4) = hv;
    *(uint2*)(Y + r * 2 * RL + RL + k4) = lv;
}

// ---------------- split-bf16 MFMA GEMM ----------------
// C = A32 @ B32^T + b1 + b2 via up-to-3 passes: Ah*Bh (+ Al*Bh) (+ Ah*Bl), fp32 acc.
// flags bit0: row perm r -> (r&15)*SEQ + (r>>4); bit1: col perm c -> (c&1023)*4 + (c>>10)
__global__ __launch_bounds__(256) void gemm_bf16_mfma(
    const ushort_t* __restrict__ A, const ushort_t* __restrict__ B,
    const float* __restrict__ b1, const float* __restrict__ b2,
    float* __restrict__ C, int Kel, int ldc, int nBase, int flags, int segs) {
    __shared__ __align__(16) ushort_t As[128 * 32];
    __shared__ __align__(16) ushort_t Bs[128 * 32];
    int tid = threadIdx.x;
    int lane = tid & 63, wave = tid >> 6;
    int wm = wave >> 1, wn = wave & 1;

    // bijective XCD swizzle (nwg % 8 == 0 in all uses)
    int nx = gridDim.x;
    int nwg = nx * gridDim.y;
    int orig = blockIdx.y * nx + blockIdx.x;
    int s = (orig & 7) * (nwg >> 3) + (orig >> 3);
    int bm = s % nx, bn = s / nx;

    f32x4 acc[4][4];
#pragma unroll
    for (int m = 0; m < 4; m++)
#pragma unroll
        for (int n = 0; n < 4; n++) acc[m][n] = (f32x4){0.f, 0.f, 0.f, 0.f};

    int srow = tid >> 1;            // 0..127: staged row
    int skh = (tid & 1) * 16;       // ushort k-offset 0/16
    const ushort_t* Abase = A + (size_t)(bm * 128 + srow) * (2 * Kel) + skh;
    const ushort_t* Bbase = B + (size_t)(bn * 128 + srow) * (2 * Kel) + skh;
    int lr = lane & 15;
    int lk = (lane >> 4) * 8;

#pragma unroll 1
    for (int seg = 0; seg < segs; seg++) {
        int aoff = (seg == 1) ? Kel : 0;     // seg0: Ah*Bh, seg1: Al*Bh, seg2: Ah*Bl
        int boff = (seg == 2) ? Kel : 0;
        for (int k0 = 0; k0 < Kel; k0 += 32) {
            uint4 a0 = *(const uint4*)(Abase + aoff + k0);
            uint4 a1 = *(const uint4*)(Abase + aoff + k0 + 8);
            uint4 b0 = *(const uint4*)(Bbase + boff + k0);
            uint4 b1v = *(const uint4*)(Bbase + boff + k0 + 8);
            __syncthreads();
            *(uint4*)(As + srow * 32 + skh) = a0;
            *(uint4*)(As + srow * 32 + skh + 8) = a1;
            *(uint4*)(Bs + srow * 32 + skh) = b0;
            *(uint4*)(Bs + srow * 32 + skh + 8) = b1v;
            __syncthreads();
            bf16x8 af[4], bfv[4];
#pragma unroll
            for (int m = 0; m < 4; m++)
                af[m] = *(const bf16x8*)(As + (wm * 64 + m * 16 + lr) * 32 + lk);
#pragma unroll
            for (int n = 0; n < 4; n++)
                bfv[n] = *(const bf16x8*)(Bs + (wn * 64 + n * 16 + lr) * 32 + lk);
#pragma unroll
            for (int m = 0; m < 4; m++)
#pragma unroll
                for (int n = 0; n < 4; n++)
                    acc[m][n] = __builtin_amdgcn_mfma_f32_16x16x32_bf16(
                        af[m], bfv[n], acc[m][n], 0, 0, 0);
        }
    }

    // epilogue: C/D layout col=lane&15, row=(lane>>4)*4+j
    int lq = lane >> 4;
#pragma unroll
    for (int n = 0; n < 4; n++) {
        int c = bn * 128 + wn * 64 + n * 16 + lr;
        float bb = (b1 ? b1[c] : 0.f) + (b2 ? b2[c] : 0.f);
        int cw = (flags & 2) ? ((c & 1023) * 4 + (c >> 10)) : c;
#pragma unroll
        for (int m = 0; m < 4; m++) {
#pragma unroll
            for (int j = 0; j < 4; j++) {
                int r = bm * 128 + wm * 64 + m * 16 + lq * 4 + j;
                int orow = (flags & 1) ? ((r & 15) * SEQ + (r >> 4)) : r;
                C[(size_t)orow * ldc + nBase + cw] = acc[m][n][j] + bb;
            }
        }
    }
}

// ---------------- PERSISTENT cooperative LSTM layer kernel ----------------
// 256 blocks x 512 threads, 1 block/CU pinned by 89 KB LDS. Weights in LDS once;
// c-state in registers; 256 steps in one launch.
// Barrier: contention-free distributed flags (own cacheline per block) +
// block-0 monitor + single 'go' broadcast. NOT cg::grid.sync (R9: 34 us/step
// from 256 serialized cross-XCD atomic RMWs on one line).
__global__ __launch_bounds__(512, 1) void lstm_persistent(
    const ushort_t* __restrict__ Wt2,  // [256][1024][16] fp16 block-tiled (this layer)
    const float* __restrict__ G,       // [4096 rows][4096] gate-interleaved (incl. biases)
    ushort_t* __restrict__ HT,         // [2][16384] fp16 parity buffers [j][b] (this layer)
    float* __restrict__ c_st,          // [16][1024] (this layer)
    float* __restrict__ Hseq,          // [4096 rows][1024] fp32
    int* __restrict__ flags,           // [256 * FLG_STRIDE], zeroed
    int* __restrict__ go) {            // [1], zeroed
    __shared__ __align__(16) ushort_t wlds[16384];   // 32 KB weights
    __shared__ __align__(16) ushort_t hs[24576];     // 48 KB (16K used; pad -> 1 blk/CU)
    __shared__ float pt[2048];                       // 8 KB
    __shared__ float gv[256];                        // 1 KB
    int tid = threadIdx.x, cb = blockIdx.x;

    // preload this block's weight slice into LDS (once)
    const uint4* wsrc = (const uint4*)(Wt2 + (size_t)cb * 16384);
    for (int i = tid; i < 2048; i += 512) ((uint4*)wlds)[i] = wsrc[i];

    int c4 = tid & 3;
    int b = (tid >> 2) & 15;
    int kg = tid >> 6;                  // 0..7
    int jl = tid & 3, bb4 = tid >> 2;   // update-thread coords (tid<64)
    float creg = 0.f;
    if (tid < 64) creg = c_st[bb4 * 1024 + cb * 4 + jl];

    int par = 0;
    for (int t = 0; t < SEQ; t++) {
        // prefetch this step's G slice (consumed 2 barriers later)
        float greg = 0.f;
        if (tid < 256)
            greg = G[((size_t)(t * BATCH + (tid >> 4))) * GATES + cb * 16 + (tid & 15)];

        // stage h(t) fp16 into LDS (32 KB, uint4)
        const uint4* hsrc = (const uint4*)(HT + par * 16384);
        for (int i = tid; i < 2048; i += 512) ((uint4*)hs)[i] = hsrc[i];
        __syncthreads();

        const ushort_t* wp = wlds + (kg * 128) * 16 + c4 * 4;
        const ushort_t* hp = hs + (kg * 128) * 16 + b;
        float4 acc = {0.f, 0.f, 0.f, 0.f};
#pragma unroll 8
        for (int kk = 0; kk < 128; kk++) {
            uint2 u = *(const uint2*)(wp + kk * 16);
            float2 f01 = __half22float2(*(const __half2*)&u.x);
            float2 f23 = __half22float2(*(const __half2*)&u.y);
            float h = __half2float(*(const __half*)(hp + kk * 16));
            acc.x += h * f01.x; acc.y += h * f01.y;
            acc.z += h * f23.x; acc.w += h * f23.y;
        }
        *(float4*)&pt[kg * 256 + b * 16 + c4 * 4] = acc;
        __syncthreads();

        if (tid < 256) {                 // reduce 8 K-chunks + base gates
            int c16 = tid & 15, bbb = tid >> 4;
            float g = greg;
#pragma unroll
            for (int q = 0; q < 8; q++) g += pt[q * 256 + bbb * 16 + c16];
            gv[tid] = g;                 // gv[bbb*16 + c16]
        }
        __syncthreads();

        if (tid < 64) {                  // state update: 4 j x 16 b
            float4 g4 = *(const float4*)&gv[bb4 * 16 + jl * 4];   // i,f,g,o
            float ig = 1.f / (1.f + __expf(-g4.x));
            float fg = 1.f / (1.f + __expf(-g4.y));
            float gg = tanhf(g4.z);
            float og = 1.f / (1.f + __expf(-g4.w));
            creg = fg * creg + ig * gg;
            float h = og * tanhf(creg);
            int j = cb * 4 + jl;
            HT[(par ^ 1) * 16384 + j * BATCH + bb4] =
                __half_as_ushort(__float2half_rn(h));
            Hseq[((size_t)(t * BATCH + bb4)) * HIDDEN + j] = h;
        }
        par ^= 1;

        // ---- fast distributed grid barrier ----
        __syncthreads();                 // drains all waves' stores to L2
        if (tid == 0) {
            __builtin_amdgcn_fence(__ATOMIC_RELEASE, "agent");   // L2 -> LLC
            __hip_atomic_store(&flags[cb * FLG_STRIDE], t + 1,
                               __ATOMIC_RELAXED, __HIP_MEMORY_SCOPE_AGENT);
        }
        if (cb == 0) {                   // monitor: 256 threads poll 256 flags
            if (tid < 256) {
                while (__hip_atomic_load(&flags[tid * FLG_STRIDE],
                                         __ATOMIC_RELAXED, __HIP_MEMORY_SCOPE_AGENT) < t + 1)
                    __builtin_amdgcn_s_sleep(1);
            }
            __syncthreads();
            if (tid == 0)
                __hip_atomic_store(go, t + 1,
                                   __ATOMIC_RELAXED, __HIP_MEMORY_SCOPE_AGENT);
        }
        if (tid == 0) {
            while (__hip_atomic_load(go, __ATOMIC_RELAXED,
                                     __HIP_MEMORY_SCOPE_AGENT) < t + 1)
                __builtin_amdgcn_s_sleep(1);
            __builtin_amdgcn_fence(__ATOMIC_ACQUIRE, "agent");   // invalidate L1/L2
        }
        __syncthreads();
    }
    if (tid < 64) c_st[bb4 * 1024 + cb * 4 + jl] = creg;
}

// ---------------- init & tails ----------------
__global__ void init_state2(const float* __restrict__ h0, const float* __restrict__ c0,
                            float* __restrict__ c_ws, ushort_t* __restrict__ HT,
                            int* __restrict__ flg) {
    int gid = blockIdx.x * 256 + threadIdx.x;  // 32768
    c_ws[gid] = c0[gid];
    int l = gid >> 14, b = (gid >> 10) & 15, j = gid & 1023;
    HT[l * 32768 + j * BATCH + b] = __half_as_ushort(__float2half_rn(h0[gid])); // parity 0
    if (gid < 16384) flg[gid] = 0;             // both layers' flags + go words
}

__global__ void write_tails2(const ushort_t* __restrict__ HT, const float* __restrict__ c_ws,
                             float* __restrict__ out) {
    int gid = blockIdx.x * 256 + threadIdx.x;  // 32768
    int l = gid >> 14, b = (gid >> 10) & 15, j = gid & 1023;
    out[LOGITS_SZ + gid] =
        __half2float(__ushort_as_half(HT[l * 32768 + j * BATCH + b]));  // final parity 0
    out[LOGITS_SZ + 32768 + gid] = c_ws[gid];
}

// ---------------- launch ----------------
extern "C" void kernel_launch(void* const* d_in, const int* in_sizes, int n_in,
                              void* d_out, int out_size, void* d_ws, size_t ws_size,
                              hipStream_t stream) {
    const int* x = (const int*)d_in[0];
    const float* h0 = (const float*)d_in[1];
    const float* c0 = (const float*)d_in[2];
    const float* emb = (const float*)d_in[3];
    const float* W_ih0 = (const float*)d_in[4];
    const float* W_hh0 = (const float*)d_in[5];
    const float* b_ih0 = (const float*)d_in[6];
    const float* b_hh0 = (const float*)d_in[7];
    const float* W_ih1 = (const float*)d_in[8];
    const float* W_hh1 = (const float*)d_in[9];
    const float* b_ih1 = (const float*)d_in[10];
    const float* b_hh1 = (const float*)d_in[11];
    const float* fc_W = (const float*)d_in[12];
    const float* fc_b = (const float*)d_in[13];
    float* out = (float*)d_out;
    float* ws = (float*)d_ws;

    // workspace layout (float offsets)
    const size_t OFF_WT0 = 0;               // Wt2_0 fp16 tiled: 2,097,152 fl
    const size_t OFF_WT1 = 4194304;         // Wt2_1 fp16 tiled: 2,097,152 fl
    const size_t OFF_X0 = 8388608;          // 2,097,152
    const size_t OFF_G = 10485760;          // 16,777,216 (ends 27,262,976)
    const size_t OFF_H0S = 27262976;        // 4,194,304
    const size_t OFF_H1S = 31457280;        // 4,194,304 (ends 35,651,584)
    const size_t OFF_C = 35651584;          // 32,768 (2 layers)
    const size_t OFF_HT = 35684352;         // 2L x 2par x 16384 halfs = 32,768 fl
    const size_t OFF_FLG = 35717120;        // 16,384 ints (both layers' barriers)

    ushort_t* HTp = (ushort_t*)(ws + OFF_HT);
    int* flg = (int*)(ws + OFF_FLG);
    // layer0: flags @ flg, go @ flg+4096 ; layer1: flags @ flg+8192, go @ flg+12288

    // phase overlays (regions dead at time of use):
    ushort_t* XHL = (ushort_t*)(ws + OFF_H0S);                 // [4096][1024] us
    ushort_t* WIH0HL = (ushort_t*)(ws + OFF_H0S + 2097152);    // [4096][1024] us
    ushort_t* AH1 = (ushort_t*)(ws + OFF_WT0);                 // [4096][2048] us (over Wt2_0, dead after L0)
    ushort_t* WIH1HL = (ushort_t*)(ws + OFF_H1S);              // [4096][2048] us
    ushort_t* Whl = (ushort_t*)ws;                             // [16000][2048] us (FC phase)
    ushort_t* Ahl = (ushort_t*)(ws + 16384000);                // [4096][2048] us

    init_state2<<<128, 256, 0, stream>>>(h0, c0, ws + OFF_C, HTp, flg);
    embed_kernel<<<MROWS, 128, 0, stream>>>(x, emb, ws + OFF_X0);
    transpose_f16_tiled<<<dim3(32, 128), 256, 0, stream>>>(W_hh0, (ushort_t*)(ws + OFF_WT0), 0, 1024);
    transpose_f16_tiled<<<dim3(32, 128), 256, 0, stream>>>(W_hh1, (ushort_t*)(ws + OFF_WT1), 0, 1024);

    // layer-0 input projection: G = X0 @ W_ih0^T + b_ih0 + b_hh0 (gate-interleaved, 3-seg)
    conv_hilo<<<MROWS, 256, 0, stream>>>(ws + OFF_X0, XHL, EMBED);
    conv_hilo<<<GATES, 256, 0, stream>>>(W_ih0, WIH0HL, EMBED);
    gemm_bf16_mfma<<<dim3(32, 32), 256, 0, stream>>>(
        XHL, WIH0HL, b_ih0, b_hh0, ws + OFF_G, EMBED, GATES, 0, 2, 3);

    // layer-0 recurrence: ONE persistent cooperative launch (fast custom barrier)
    {
        const ushort_t* wt = (const ushort_t*)(ws + OFF_WT0);
        const float* gp = ws + OFF_G;
        ushort_t* ht = HTp;
        float* cp = ws + OFF_C;
        float* hq = ws + OFF_H0S;
        int* fl = flg;
        int* go = flg + 4096;
        void* args[] = {(void*)&wt, (void*)&gp, (void*)&ht, (void*)&cp, (void*)&hq,
                        (void*)&fl, (void*)&go};
        hipLaunchCooperativeKernel((void*)lstm_persistent, dim3(256), dim3(512),
                                   args, 0, stream);
    }

    // layer-1 input projection: G = H0S @ W_ih1^T + b_ih1 + b_hh1 (gate-interleaved, 3-seg)
    conv_hilo<<<MROWS, 256, 0, stream>>>(ws + OFF_H0S, AH1, HIDDEN);
    conv_hilo<<<GATES, 256, 0, stream>>>(W_ih1, WIH1HL, HIDDEN);
    gemm_bf16_mfma<<<dim3(32, 32), 256, 0, stream>>>(
        AH1, WIH1HL, b_ih1, b_hh1, ws + OFF_G, HIDDEN, GATES, 0, 2, 3);

    // layer-1 recurrence
    {
        const ushort_t* wt = (const ushort_t*)(ws + OFF_WT1);
        const float* gp = ws + OFF_G;
        ushort_t* ht = HTp + 32768;
        float* cp = ws + OFF_C + BATCH * HIDDEN;
        float* hq = ws + OFF_H1S;
        int* fl = flg + 8192;
        int* go = flg + 12288;
        void* args[] = {(void*)&wt, (void*)&gp, (void*)&ht, (void*)&cp, (void*)&hq,
                        (void*)&fl, (void*)&go};
        hipLaunchCooperativeKernel((void*)lstm_persistent, dim3(256), dim3(512),
                                   args, 0, stream);
    }

    // FC via split-bf16 MFMA (2-seg): logits[b][s][v]
    conv_hilo<<<MROWS, 256, 0, stream>>>(ws + OFF_H1S, Ahl, HIDDEN);
    for (int half = 0; half < 2; half++) {
        conv_hilo<<<16000, 256, 0, stream>>>(fc_W + (size_t)half * 16000 * HIDDEN, Whl, HIDDEN);
        gemm_bf16_mfma<<<dim3(32, 125), 256, 0, stream>>>(
            Ahl, Whl, fc_b, nullptr, out, HIDDEN, VOCAB, half * 16000, 1, 2);
    }

    write_tails2<<<128, 256, 0, stream>>>(HTp, ws + OFF_C, out);
}

// Round 11
// 6540.640 us; speedup vs baseline: 3.0108x; 1.3063x over previous
//
#include <hip/hip_runtime.h>
#include <hip/hip_bf16.h>
#include <hip/hip_fp16.h>
#include <hip/hip_cooperative_groups.h>
#include <cmath>

// Problem constants
#define BATCH 16
#define SEQ 256
#define EMBED 512
#define HIDDEN 1024
#define GATES 4096       // 4*HIDDEN
#define VOCAB 32000
#define MROWS 4096       // BATCH*SEQ
#define LOGITS_SZ 131072000  // 16*256*32000
#define FLG_STRIDE 16    // one cacheline (64 B) per flag

typedef unsigned short ushort_t;
typedef unsigned int uint_t;
typedef __attribute__((ext_vector_type(8))) __bf16 bf16x8;
typedef __attribute__((ext_vector_type(4))) float f32x4;

// ---------------- embedding gather ----------------
__global__ void embed_kernel(const int* __restrict__ x, const float* __restrict__ emb,
                             float* __restrict__ X0) {
    int r = blockIdx.x;            // r = s*16 + b
    int s = r >> 4, b = r & 15;
    int tok = x[b * SEQ + s];
    const float4* src = (const float4*)(emb + (size_t)tok * EMBED);
    float4* dst = (float4*)(X0 + (size_t)r * EMBED);
    for (int i = threadIdx.x; i < EMBED / 4; i += blockDim.x) dst[i] = src[i];
}

// ---------------- transpose + gate-interleave + BLOCK-TILED fp16 pack ----------------
// W [4096][1024] (rows = gate*1024 + j) -> T[cb][kOff+k][c16] fp16, where
// col' = j*4 + gate, cb = col'>>4, c16 = col'&15.
__global__ void transpose_f16_tiled(const float* __restrict__ W, ushort_t* __restrict__ T,
                                    int kOff, int kTot) {
    __shared__ float tile[32][33];
    int c0 = blockIdx.x * 32, r0 = blockIdx.y * 32;   // c0: k range, r0: W-row range
    int tx = threadIdx.x & 31, ty = threadIdx.x >> 5; // 256 threads: ty 0..7
    for (int i = ty; i < 32; i += 8)
        tile[i][tx] = W[(size_t)(r0 + i) * HIDDEN + (c0 + tx)];
    __syncthreads();
    int g = r0 >> 10, j0 = r0 & 1023;
    for (int i = ty; i < 32; i += 8) {
        int colp = (j0 + tx) * 4 + g;
        int cb = colp >> 4, c16 = colp & 15;
        int k = kOff + c0 + i;
        T[((size_t)cb * kTot + k) * 16 + c16] =
            __half_as_ushort(__float2half_rn(tile[tx][i]));
    }
}

// ---------------- fp32 -> bf16 hi/lo split: X[r][RL] -> Y[r][2*RL] ----------------
__device__ __forceinline__ unsigned f2bf(float f) {
    unsigned u = __float_as_uint(f);
    return (u + 0x7FFFu + ((u >> 16) & 1u)) >> 16;   // RNE
}

__global__ __launch_bounds__(256) void conv_hilo(const float* __restrict__ X,
                                                 ushort_t* __restrict__ Y, int RL) {
    size_t r = blockIdx.x;
    int k4 = threadIdx.x * 4;
    if (k4 >= RL) return;
    float4 v = *(const float4*)(X + r * RL + k4);
    unsigned h0 = f2bf(v.x), h1 = f2bf(v.y), h2 = f2bf(v.z), h3 = f2bf(v.w);
    unsigned l0 = f2bf(v.x - __uint_as_float(h0 << 16));
    unsigned l1 = f2bf(v.y - __uint_as_float(h1 << 16));
    unsigned l2 = f2bf(v.z - __uint_as_float(h2 << 16));
    unsigned l3 = f2bf(v.w - __uint_as_float(h3 << 16));
    uint2 hv, lv;
    hv.x = h0 | (h1 << 16); hv.y = h2 | (h3 << 16);
    lv.x = l0 | (l1 << 16); lv.y = l2 | (l3 << 16);
    *(uint2*)(Y + r * 2 * RL + k4) = hv;
    *(uint2*)(Y + r * 2 * RL + RL + k4) = lv;
}

// ---------------- split-bf16 MFMA GEMM ----------------
// C = A32 @ B32^T + b1 + b2 via up-to-3 passes: Ah*Bh (+ Al*Bh) (+ Ah*Bl), fp32 acc.
// flags bit0: row perm r -> (r&15)*SEQ + (r>>4); bit1: col perm c -> (c&1023)*4 + (c>>10)
__global__ __launch_bounds__(256) void gemm_bf16_mfma(
    const ushort_t* __restrict__ A, const ushort_t* __restrict__ B,
    const float* __restrict__ b1, const float* __restrict__ b2,
    float* __restrict__ C, int Kel, int ldc, int nBase, int flags, int segs) {
    __shared__ __align__(16) ushort_t As[128 * 32];
    __shared__ __align__(16) ushort_t Bs[128 * 32];
    int tid = threadIdx.x;
    int lane = tid & 63, wave = tid >> 6;
    int wm = wave >> 1, wn = wave & 1;

    // bijective XCD swizzle (nwg % 8 == 0 in all uses)
    int nx = gridDim.x;
    int nwg = nx * gridDim.y;
    int orig = blockIdx.y * nx + blockIdx.x;
    int s = (orig & 7) * (nwg >> 3) + (orig >> 3);
    int bm = s % nx, bn = s / nx;

    f32x4 acc[4][4];
#pragma unroll
    for (int m = 0; m < 4; m++)
#pragma unroll
        for (int n = 0; n < 4; n++) acc[m][n] = (f32x4){0.f, 0.f, 0.f, 0.f};

    int srow = tid >> 1;            // 0..127: staged row
    int skh = (tid & 1) * 16;       // ushort k-offset 0/16
    const ushort_t* Abase = A + (size_t)(bm * 128 + srow) * (2 * Kel) + skh;
    const ushort_t* Bbase = B + (size_t)(bn * 128 + srow) * (2 * Kel) + skh;
    int lr = lane & 15;
    int lk = (lane >> 4) * 8;

#pragma unroll 1
    for (int seg = 0; seg < segs; seg++) {
        int aoff = (seg == 1) ? Kel : 0;     // seg0: Ah*Bh, seg1: Al*Bh, seg2: Ah*Bl
        int boff = (seg == 2) ? Kel : 0;
        for (int k0 = 0; k0 < Kel; k0 += 32) {
            uint4 a0 = *(const uint4*)(Abase + aoff + k0);
            uint4 a1 = *(const uint4*)(Abase + aoff + k0 + 8);
            uint4 b0 = *(const uint4*)(Bbase + boff + k0);
            uint4 b1v = *(const uint4*)(Bbase + boff + k0 + 8);
            __syncthreads();
            *(uint4*)(As + srow * 32 + skh) = a0;
            *(uint4*)(As + srow * 32 + skh + 8) = a1;
            *(uint4*)(Bs + srow * 32 + skh) = b0;
            *(uint4*)(Bs + srow * 32 + skh + 8) = b1v;
            __syncthreads();
            bf16x8 af[4], bfv[4];
#pragma unroll
            for (int m = 0; m < 4; m++)
                af[m] = *(const bf16x8*)(As + (wm * 64 + m * 16 + lr) * 32 + lk);
#pragma unroll
            for (int n = 0; n < 4; n++)
                bfv[n] = *(const bf16x8*)(Bs + (wn * 64 + n * 16 + lr) * 32 + lk);
#pragma unroll
            for (int m = 0; m < 4; m++)
#pragma unroll
                for (int n = 0; n < 4; n++)
                    acc[m][n] = __builtin_amdgcn_mfma_f32_16x16x32_bf16(
                        af[m], bfv[n], acc[m][n], 0, 0, 0);
        }
    }

    // epilogue: C/D layout col=lane&15, row=(lane>>4)*4+j
    int lq = lane >> 4;
#pragma unroll
    for (int n = 0; n < 4; n++) {
        int c = bn * 128 + wn * 64 + n * 16 + lr;
        float bb = (b1 ? b1[c] : 0.f) + (b2 ? b2[c] : 0.f);
        int cw = (flags & 2) ? ((c & 1023) * 4 + (c >> 10)) : c;
#pragma unroll
        for (int m = 0; m < 4; m++) {
#pragma unroll
            for (int j = 0; j < 4; j++) {
                int r = bm * 128 + wm * 64 + m * 16 + lq * 4 + j;
                int orow = (flags & 1) ? ((r & 15) * SEQ + (r >> 4)) : r;
                C[(size_t)orow * ldc + nBase + cw] = acc[m][n][j] + bb;
            }
        }
    }
}

// ---------------- PERSISTENT cooperative LSTM layer kernel ----------------
// 256 blocks x 512 threads, 1 block/CU pinned by 89 KB LDS. Weights in LDS once;
// c-state in registers; 256 steps in one launch.
// FENCE-FREE handoff: h parity buffers are accessed ONLY via agent-scope relaxed
// atomic uints (LLC-coherent, bypass L2 — same mechanism as the flags, proven in
// R10). __syncthreads drains vmcnt before the flag store, ordering h before flag.
// Barrier: single-hop all-to-all — each block stores its own cacheline-strided
// flag; all 256 threads poll all 256 flags in parallel. No monitor, no go word,
// no wbl2/inv fences (R10: fences + 2-hop barrier cost ~11 us/step).
__global__ __launch_bounds__(512, 1) void lstm_persistent(
    const ushort_t* __restrict__ Wt2,  // [256][1024][16] fp16 block-tiled (this layer)
    const float* __restrict__ G,       // [4096 rows][4096] gate-interleaved (incl. biases)
    ushort_t* __restrict__ HT,         // [2][16384] fp16 parity buffers [j][b] (this layer)
    float* __restrict__ c_st,          // [16][1024] (this layer)
    float* __restrict__ Hseq,          // [4096 rows][1024] fp32
    int* __restrict__ flags) {         // [256 * FLG_STRIDE], zeroed
    __shared__ __align__(16) ushort_t wlds[16384];   // 32 KB weights
    __shared__ __align__(16) ushort_t hs[24576];     // 48 KB (32K used; pad -> 1 blk/CU)
    __shared__ float pt[2048];                       // 8 KB
    __shared__ float gv[256];                        // 1 KB
    __shared__ ushort_t hout[64];
    int tid = threadIdx.x, cb = blockIdx.x;

    // preload this block's weight slice into LDS (once)
    const uint4* wsrc = (const uint4*)(Wt2 + (size_t)cb * 16384);
    for (int i = tid; i < 2048; i += 512) ((uint4*)wlds)[i] = wsrc[i];

    int c4 = tid & 3;
    int b = (tid >> 2) & 15;
    int kg = tid >> 6;                  // 0..7
    int jl = tid & 3, bb4 = tid >> 2;   // update-thread coords (tid<64)
    float creg = 0.f;
    if (tid < 64) creg = c_st[bb4 * 1024 + cb * 4 + jl];

    int par = 0;
    for (int t = 0; t < SEQ; t++) {
        // prefetch this step's G slice (L2-cacheable — no invalidation anymore)
        float greg = 0.f;
        if (tid < 256)
            greg = G[((size_t)(t * BATCH + (tid >> 4))) * GATES + cb * 16 + (tid & 15)];

        // stage h(t): agent-scope atomic uint loads (read LLC directly)
        const uint_t* hsrc = (const uint_t*)(HT + par * 16384);
        uint_t* hdst = (uint_t*)hs;
#pragma unroll
        for (int i = 0; i < 16; i++) {
            int idx = tid + i * 512;
            hdst[idx] = __hip_atomic_load(hsrc + idx, __ATOMIC_RELAXED,
                                          __HIP_MEMORY_SCOPE_AGENT);
        }
        __syncthreads();

        const ushort_t* wp = wlds + (kg * 128) * 16 + c4 * 4;
        const ushort_t* hp = hs + (kg * 128) * 16 + b;
        float4 acc = {0.f, 0.f, 0.f, 0.f};
#pragma unroll 8
        for (int kk = 0; kk < 128; kk++) {
            uint2 u = *(const uint2*)(wp + kk * 16);
            float2 f01 = __half22float2(*(const __half2*)&u.x);
            float2 f23 = __half22float2(*(const __half2*)&u.y);
            float h = __half2float(*(const __half*)(hp + kk * 16));
            acc.x += h * f01.x; acc.y += h * f01.y;
            acc.z += h * f23.x; acc.w += h * f23.y;
        }
        *(float4*)&pt[kg * 256 + b * 16 + c4 * 4] = acc;
        __syncthreads();

        if (tid < 256) {                 // reduce 8 K-chunks + base gates
            int c16 = tid & 15, bbb = tid >> 4;
            float g = greg;
#pragma unroll
            for (int q = 0; q < 8; q++) g += pt[q * 256 + bbb * 16 + c16];
            gv[tid] = g;                 // gv[bbb*16 + c16]
        }
        __syncthreads();

        if (tid < 64) {                  // state update: 4 j x 16 b
            float4 g4 = *(const float4*)&gv[bb4 * 16 + jl * 4];   // i,f,g,o
            float ig = 1.f / (1.f + __expf(-g4.x));
            float fg = 1.f / (1.f + __expf(-g4.y));
            float gg = tanhf(g4.z);
            float og = 1.f / (1.f + __expf(-g4.w));
            creg = fg * creg + ig * gg;
            float h = og * tanhf(creg);
            hout[jl * 16 + bb4] = __half_as_ushort(__float2half_rn(h));
            Hseq[((size_t)(t * BATCH + bb4)) * HIDDEN + cb * 4 + jl] = h;
        }
        __syncthreads();
        if (tid < 32) {                  // publish h-slice: agent-scope atomic stores
            int j2 = tid >> 3, bp = tid & 7;
            uint_t lo = hout[j2 * 16 + 2 * bp];
            uint_t hi = hout[j2 * 16 + 2 * bp + 1];
            uint_t* dst = (uint_t*)(HT + (par ^ 1) * 16384 + (cb * 4 + j2) * 16) + bp;
            __hip_atomic_store(dst, lo | (hi << 16), __ATOMIC_RELAXED,
                               __HIP_MEMORY_SCOPE_AGENT);
        }
        par ^= 1;

        if (t == SEQ - 1) break;         // no barrier needed after final step

        // ---- single-hop all-to-all grid barrier ----
        __syncthreads();                 // s_waitcnt vmcnt(0): h stores at LLC
        if (tid == 0)
            __hip_atomic_store(&flags[cb * FLG_STRIDE], t + 1, __ATOMIC_RELAXED,
                               __HIP_MEMORY_SCOPE_AGENT);
        if (tid < 256) {
            while (__hip_atomic_load(&flags[tid * FLG_STRIDE], __ATOMIC_RELAXED,
                                     __HIP_MEMORY_SCOPE_AGENT) < t + 1)
                __builtin_amdgcn_s_sleep(2);
        }
        __syncthreads();
    }
    if (tid < 64) c_st[bb4 * 1024 + cb * 4 + jl] = creg;
}

// ---------------- init & tails ----------------
__global__ void init_state2(const float* __restrict__ h0, const float* __restrict__ c0,
                            float* __restrict__ c_ws, ushort_t* __restrict__ HT,
                            int* __restrict__ flg) {
    int gid = blockIdx.x * 256 + threadIdx.x;  // 32768
    c_ws[gid] = c0[gid];
    int l = gid >> 14, b = (gid >> 10) & 15, j = gid & 1023;
    HT[l * 32768 + j * BATCH + b] = __half_as_ushort(__float2half_rn(h0[gid])); // parity 0
    if (gid < 16384) flg[gid] = 0;             // both layers' flag regions
}

__global__ void write_tails2(const ushort_t* __restrict__ HT, const float* __restrict__ c_ws,
                             float* __restrict__ out) {
    int gid = blockIdx.x * 256 + threadIdx.x;  // 32768
    int l = gid >> 14, b = (gid >> 10) & 15, j = gid & 1023;
    out[LOGITS_SZ + gid] =
        __half2float(__ushort_as_half(HT[l * 32768 + j * BATCH + b]));  // final parity 0
    out[LOGITS_SZ + 32768 + gid] = c_ws[gid];
}

// ---------------- launch ----------------
extern "C" void kernel_launch(void* const* d_in, const int* in_sizes, int n_in,
                              void* d_out, int out_size, void* d_ws, size_t ws_size,
                              hipStream_t stream) {
    const int* x = (const int*)d_in[0];
    const float* h0 = (const float*)d_in[1];
    const float* c0 = (const float*)d_in[2];
    const float* emb = (const float*)d_in[3];
    const float* W_ih0 = (const float*)d_in[4];
    const float* W_hh0 = (const float*)d_in[5];
    const float* b_ih0 = (const float*)d_in[6];
    const float* b_hh0 = (const float*)d_in[7];
    const float* W_ih1 = (const float*)d_in[8];
    const float* W_hh1 = (const float*)d_in[9];
    const float* b_ih1 = (const float*)d_in[10];
    const float* b_hh1 = (const float*)d_in[11];
    const float* fc_W = (const float*)d_in[12];
    const float* fc_b = (const float*)d_in[13];
    float* out = (float*)d_out;
    float* ws = (float*)d_ws;

    // workspace layout (float offsets)
    const size_t OFF_WT0 = 0;               // Wt2_0 fp16 tiled: 2,097,152 fl
    const size_t OFF_WT1 = 4194304;         // Wt2_1 fp16 tiled: 2,097,152 fl
    const size_t OFF_X0 = 8388608;          // 2,097,152
    const size_t OFF_G = 10485760;          // 16,777,216 (ends 27,262,976)
    const size_t OFF_H0S = 27262976;        // 4,194,304
    const size_t OFF_H1S = 31457280;        // 4,194,304 (ends 35,651,584)
    const size_t OFF_C = 35651584;          // 32,768 (2 layers)
    const size_t OFF_HT = 35684352;         // 2L x 2par x 16384 halfs = 32,768 fl
    const size_t OFF_FLG = 35717120;        // 16,384 ints (both layers' barriers)

    ushort_t* HTp = (ushort_t*)(ws + OFF_HT);
    int* flg = (int*)(ws + OFF_FLG);
    // layer0: flags @ flg ; layer1: flags @ flg+8192

    // phase overlays (regions dead at time of use):
    ushort_t* XHL = (ushort_t*)(ws + OFF_H0S);                 // [4096][1024] us
    ushort_t* WIH0HL = (ushort_t*)(ws + OFF_H0S + 2097152);    // [4096][1024] us
    ushort_t* AH1 = (ushort_t*)(ws + OFF_WT0);                 // [4096][2048] us (over Wt2_0, dead after L0)
    ushort_t* WIH1HL = (ushort_t*)(ws + OFF_H1S);              // [4096][2048] us
    ushort_t* Whl = (ushort_t*)ws;                             // [16000][2048] us (FC phase)
    ushort_t* Ahl = (ushort_t*)(ws + 16384000);                // [4096][2048] us

    init_state2<<<128, 256, 0, stream>>>(h0, c0, ws + OFF_C, HTp, flg);
    embed_kernel<<<MROWS, 128, 0, stream>>>(x, emb, ws + OFF_X0);
    transpose_f16_tiled<<<dim3(32, 128), 256, 0, stream>>>(W_hh0, (ushort_t*)(ws + OFF_WT0), 0, 1024);
    transpose_f16_tiled<<<dim3(32, 128), 256, 0, stream>>>(W_hh1, (ushort_t*)(ws + OFF_WT1), 0, 1024);

    // layer-0 input projection: G = X0 @ W_ih0^T + b_ih0 + b_hh0 (gate-interleaved, 3-seg)
    conv_hilo<<<MROWS, 256, 0, stream>>>(ws + OFF_X0, XHL, EMBED);
    conv_hilo<<<GATES, 256, 0, stream>>>(W_ih0, WIH0HL, EMBED);
    gemm_bf16_mfma<<<dim3(32, 32), 256, 0, stream>>>(
        XHL, WIH0HL, b_ih0, b_hh0, ws + OFF_G, EMBED, GATES, 0, 2, 3);

    // layer-0 recurrence: ONE persistent cooperative launch (fence-free barrier)
    {
        const ushort_t* wt = (const ushort_t*)(ws + OFF_WT0);
        const float* gp = ws + OFF_G;
        ushort_t* ht = HTp;
        float* cp = ws + OFF_C;
        float* hq = ws + OFF_H0S;
        int* fl = flg;
        void* args[] = {(void*)&wt, (void*)&gp, (void*)&ht, (void*)&cp, (void*)&hq,
                        (void*)&fl};
        hipLaunchCooperativeKernel((void*)lstm_persistent, dim3(256), dim3(512),
                                   args, 0, stream);
    }

    // layer-1 input projection: G = H0S @ W_ih1^T + b_ih1 + b_hh1 (gate-interleaved, 3-seg)
    conv_hilo<<<MROWS, 256, 0, stream>>>(ws + OFF_H0S, AH1, HIDDEN);
    conv_hilo<<<GATES, 256, 0, stream>>>(W_ih1, WIH1HL, HIDDEN);
    gemm_bf16_mfma<<<dim3(32, 32), 256, 0, stream>>>(
        AH1, WIH1HL, b_ih1, b_hh1, ws + OFF_G, HIDDEN, GATES, 0, 2, 3);

    // layer-1 recurrence
    {
        const ushort_t* wt = (const ushort_t*)(ws + OFF_WT1);
        const float* gp = ws + OFF_G;
        ushort_t* ht = HTp + 32768;
        float* cp = ws + OFF_C + BATCH * HIDDEN;
        float* hq = ws + OFF_H1S;
        int* fl = flg + 8192;
        void* args[] = {(void*)&wt, (void*)&gp, (void*)&ht, (void*)&cp, (void*)&hq,
                        (void*)&fl};
        hipLaunchCooperativeKernel((void*)lstm_persistent, dim3(256), dim3(512),
                                   args, 0, stream);
    }

    // FC via split-bf16 MFMA (2-seg): logits[b][s][v]
    conv_hilo<<<MROWS, 256, 0, stream>>>(ws + OFF_H1S, Ahl, HIDDEN);
    for (int half = 0; half < 2; half++) {
        conv_hilo<<<16000, 256, 0, stream>>>(fc_W + (size_t)half * 16000 * HIDDEN, Whl, HIDDEN);
        gemm_bf16_mfma<<<dim3(32, 125), 256, 0, stream>>>(
            Ahl, Whl, fc_b, nullptr, out, HIDDEN, VOCAB, half * 16000, 1, 2);
    }

    write_tails2<<<128, 256, 0, stream>>>(HTp, ws + OFF_C, out);
}